// Round 16
// baseline (900.915 us; speedup 1.0000x reference)
//
#include <hip/hip_runtime.h>
#include <hip/hip_bf16.h>

#define B_TOK 16384
#define TOPK 2
#define NEXP 64
#define HID 512
#define FFN 1024
#define NASSIGN (B_TOK * TOPK)   // 32768
#define CAP (NASSIGN / NEXP)     // 512 assignments per expert (balanced)

typedef unsigned short u16;
typedef __bf16 bf16_t;
typedef bf16_t bf16x8 __attribute__((ext_vector_type(8)));
typedef float f32x4 __attribute__((ext_vector_type(4)));

// native cvt: compiler emits v_cvt_pk_bf16_f32 (RTNE)
__device__ __forceinline__ unsigned pkbf(float a, float b) {
  union { bf16_t h[2]; unsigned u; } v;
  v.h[0] = (bf16_t)a; v.h[1] = (bf16_t)b;
  return v.u;
}
__device__ __forceinline__ u16 f2bf(float f) {
  union { bf16_t h; u16 u; } v; v.h = (bf16_t)f; return v.u;
}
__device__ __forceinline__ float bf2f(unsigned u16v) {
  union { unsigned u; float f; } v; v.u = u16v << 16; return v.f;
}

#define GLOAD_LDS16(g, l)                                                     \
  __builtin_amdgcn_global_load_lds((const __attribute__((address_space(1))) void*)(g), \
                                   (__attribute__((address_space(3))) void*)(l), 16, 0, 0)

// ---------------------------------------------------------------- routing
__global__ void k_route(const int* __restrict__ ids, int* __restrict__ cnt,
                        int* __restrict__ tok_of, int* __restrict__ slot_pos) {
  int n = blockIdx.x * blockDim.x + threadIdx.x;
  if (n >= NASSIGN) return;
  int e = ids[n];
  int r = atomicAdd(&cnt[e], 1);
  int p = e * CAP + r;
  tok_of[p] = n >> 1;
  slot_pos[n] = p;
}

// ------------------------------------------------- gather + fp32->bf16 cast
__global__ void k_gather(const float* __restrict__ hs, const int* __restrict__ tok_of,
                         u16* __restrict__ Xg) {
  int p = blockIdx.x * 4 + (threadIdx.x >> 6);
  int lane = threadIdx.x & 63;
  const float4* src = reinterpret_cast<const float4*>(hs + (size_t)tok_of[p] * HID);
  uint2* dst = reinterpret_cast<uint2*>(Xg + (size_t)p * HID);
#pragma unroll
  for (int i = 0; i < 2; i++) {
    float4 v = src[i * 64 + lane];
    uint2 o;
    o.x = pkbf(v.x, v.y);
    o.y = pkbf(v.z, v.w);
    dst[i * 64 + lane] = o;
  }
}

// --------------------------------------------- grouped GEMM1 (BK=32, 64KB LDS)
// Same 256x256 / 8-wave / 4-phase skeleton as k_gemm below, but BK=32 so the
// LDS footprint is 64KB -> 2 blocks/CU (cross-block TLP fills barrier stalls).
// Tiles: A [256r][32k], B [256n][32k] bf16; row=64B=4 chunks; swizzle (both
// sides, rule #21): slot = (c ^ ((r ^ (r>>2)) & 3)) -- enumerated conflict-free
// for frag reads (16 lanes span all 8 bank-groups 2x).
// One bf16x8 frag = full K=32 -> 12 ds_read_b128 + 32 MFMA per K-tile.
// B staged by waves 0-3 only (8 float4 loads, 4 uint4 swizzled writes).
// vmcnt: ph3 waits vmcnt(2) = retires ADMA(t+1)+L(t+1), leaves ADMA(t+2).
template <int K, int NN, bool SILU>
__global__ __launch_bounds__(512, 4) void k_gemm1(const u16* __restrict__ A,
                                                  const float* __restrict__ Wf,
                                                  u16* __restrict__ Cout) {
  constexpr int MT = CAP / 256;        // 2
  constexpr int NT = NN / 256;
  constexpr int NWG = NEXP * MT * NT;  // %8 == 0
  constexpr int Q = NWG / 8;
  constexpr int KT = K / 32;           // 16
  int wg = (blockIdx.x % 8) * Q + blockIdx.x / 8;  // XCD chunked swizzle
  int e = wg / (MT * NT);
  int rm = wg % (MT * NT);
  int mt = rm / NT, nt = rm % NT;

  const u16* Ab = A + ((size_t)e * CAP + (size_t)mt * 256) * K;

  // LDS: A dbuf 2x16KB at 0; B dbuf 2x16KB at 32768. 64KB.
  __shared__ __align__(16) char smc[65536];

  int t_ = threadIdx.x;
  int lane = t_ & 63, wv = t_ >> 6;
  int wm = wv >> 2, wn = wv & 3;        // 2x4 wave grid; wave out = 128x64
  int l15 = lane & 15, lhi = lane >> 4;

  // ---- A staging: call j covers rows j*128..+127; thread t_ -> row t_>>2,
  // phys pos t_&3; source logical chunk = pos ^ S2(row),
  // S2(row) = ((t_>>2)&3) ^ ((t_>>4)&3)  (j*128 doesn't change S2).
  int arow = t_ >> 2;
  int s2a = ((t_ >> 2) & 3) ^ ((t_ >> 4) & 3);
  int gchunk = (t_ & 3) ^ s2a;
  const u16* gA = Ab + (size_t)arow * K + gchunk * 8;
#define STAGE_A1(tn)                                                         \
  do {                                                                       \
    char* d_ = smc + ((tn) & 1) * 16384 + wv * 1024;                         \
    GLOAD_LDS16(gA + (size_t)(tn) * 32, d_);                                 \
    GLOAD_LDS16(gA + (size_t)128 * K + (size_t)(tn) * 32, d_ + 8192);        \
  } while (0)

  // ---- B staging (waves 0-3): kunit = t_>>6 (0..3 active; k=kunit*8..+7),
  // nunit = t_&63 -> cols n0..n0+3. 8 float4 loads, 4 uint4 writes.
  int kunit = t_ >> 6;
  int nunit = t_ & 63;
  const float* gWb = Wf + (size_t)e * K * NN + (size_t)((kunit & 3) * 8) * NN +
                     (size_t)nt * 256 + nunit * 4;
  int wbo[4];
#pragma unroll
  for (int i = 0; i < 4; i++) {
    int n = nunit * 4 + i;
    int s2 = (n ^ (n >> 2)) & 3;
    wbo[i] = n * 64 + (((kunit & 3) ^ s2) & 3) * 16;
  }

  f32x4 acc[8][4];
#pragma unroll
  for (int i = 0; i < 8; i++)
#pragma unroll
    for (int j = 0; j < 4; j++) {
      f32x4 z = {0.f, 0.f, 0.f, 0.f};
      acc[i][j] = z;
    }
  bf16x8 a[4], b[4];

  // ---- fragment read offsets (within one 16KB buffer)
  int aof[8], bof[4];
#pragma unroll
  for (int mf = 0; mf < 8; mf++) {
    int r = wm * 128 + mf * 16 + l15;
    aof[mf] = r * 64 + ((lhi ^ ((r ^ (r >> 2)) & 3)) & 3) * 16;
  }
#pragma unroll
  for (int nf = 0; nf < 4; nf++) {
    int r = wn * 64 + nf * 16 + l15;
    bof[nf] = r * 64 + ((lhi ^ ((r ^ (r >> 2)) & 3)) & 3) * 16;
  }

#define LGKM0_BAR()                                                          \
  do {                                                                       \
    asm volatile("s_waitcnt lgkmcnt(0)" ::: "memory");                       \
    __builtin_amdgcn_sched_barrier(0);                                       \
    __builtin_amdgcn_s_barrier();                                            \
  } while (0)

#define MFMA_OCT(mh, nh)                                                     \
  do {                                                                       \
    __builtin_amdgcn_s_setprio(1);                                           \
    _Pragma("unroll") for (int mf = 0; mf < 4; mf++)                         \
        _Pragma("unroll") for (int nf = 0; nf < 2; nf++)                     \
            acc[(mh)*4 + mf][(nh)*2 + nf] = __builtin_amdgcn_mfma_f32_16x16x32_bf16( \
                a[mf], b[(nh)*2 + nf], acc[(mh)*4 + mf][(nh)*2 + nf], 0, 0, 0); \
    __builtin_amdgcn_s_setprio(0);                                           \
  } while (0)

#define WRITE_B1(tn)                                                         \
  do {                                                                       \
    char* w_ = smc + 32768 + ((tn) & 1) * 16384;                             \
    _Pragma("unroll") for (int i = 0; i < 4; i++) {                          \
      uint4 v;                                                               \
      v.x = pkbf(L0[i], L1[i]); v.y = pkbf(L2[i], L3[i]);                    \
      v.z = pkbf(L4[i], L5[i]); v.w = pkbf(L6[i], L7[i]);                    \
      *reinterpret_cast<uint4*>(w_ + wbo[i]) = v;                            \
    }                                                                        \
  } while (0)

  // ---- prologue: A(0), A(1) DMA; B(0) reg-staged into slot 0
  STAGE_A1(0);
  STAGE_A1(1);
  {
    if (t_ < 256) {
      float4 L0, L1, L2, L3, L4, L5, L6, L7;
      L0 = *reinterpret_cast<const float4*>(gWb);
      L1 = *reinterpret_cast<const float4*>(gWb + (size_t)1 * NN);
      L2 = *reinterpret_cast<const float4*>(gWb + (size_t)2 * NN);
      L3 = *reinterpret_cast<const float4*>(gWb + (size_t)3 * NN);
      L4 = *reinterpret_cast<const float4*>(gWb + (size_t)4 * NN);
      L5 = *reinterpret_cast<const float4*>(gWb + (size_t)5 * NN);
      L6 = *reinterpret_cast<const float4*>(gWb + (size_t)6 * NN);
      L7 = *reinterpret_cast<const float4*>(gWb + (size_t)7 * NN);
      asm volatile("s_waitcnt vmcnt(0)" ::: "memory");
      __builtin_amdgcn_sched_barrier(0);
      WRITE_B1(0);
    } else {
      asm volatile("s_waitcnt vmcnt(0)" ::: "memory");
    }
  }
  LGKM0_BAR();

  for (int t = 0; t < KT; t++) {
    const char* pA = smc + (t & 1) * 16384;
    const char* pB = smc + 32768 + (t & 1) * 16384;
    float4 L0, L1, L2, L3, L4, L5, L6, L7;

    // ---------------- phase 0: frags a03 + b01; issue L0..3(t+1)
#pragma unroll
    for (int mf = 0; mf < 4; mf++)
      a[mf] = *reinterpret_cast<const bf16x8*>(pA + aof[mf]);
#pragma unroll
    for (int nf = 0; nf < 2; nf++)
      b[nf] = *reinterpret_cast<const bf16x8*>(pB + bof[nf]);
    if (t + 1 < KT && t_ < 256) {
      const float* g = gWb + (size_t)(t + 1) * 32 * NN;
      L0 = *reinterpret_cast<const float4*>(g);
      L1 = *reinterpret_cast<const float4*>(g + (size_t)1 * NN);
      L2 = *reinterpret_cast<const float4*>(g + (size_t)2 * NN);
      L3 = *reinterpret_cast<const float4*>(g + (size_t)3 * NN);
    }
    LGKM0_BAR();
    MFMA_OCT(0, 0);
    __builtin_amdgcn_s_barrier();

    // ---------------- phase 1: frags b23; issue L4..7(t+1)
#pragma unroll
    for (int nf = 0; nf < 2; nf++)
      b[2 + nf] = *reinterpret_cast<const bf16x8*>(pB + bof[2 + nf]);
    if (t + 1 < KT && t_ < 256) {
      const float* g = gWb + (size_t)(t + 1) * 32 * NN;
      L4 = *reinterpret_cast<const float4*>(g + (size_t)4 * NN);
      L5 = *reinterpret_cast<const float4*>(g + (size_t)5 * NN);
      L6 = *reinterpret_cast<const float4*>(g + (size_t)6 * NN);
      L7 = *reinterpret_cast<const float4*>(g + (size_t)7 * NN);
    }
    LGKM0_BAR();
    MFMA_OCT(0, 1);
    __builtin_amdgcn_s_barrier();

    // ---------------- phase 2: frags a47 (all A-reads of tile t done here)
#pragma unroll
    for (int mf = 0; mf < 4; mf++)
      a[mf] = *reinterpret_cast<const bf16x8*>(pA + aof[4 + mf]);
    LGKM0_BAR();
    MFMA_OCT(1, 0);
    __builtin_amdgcn_s_barrier();

    // ---------------- phase 3: A(t+2) DMA; counted vmcnt; uint4 B-writes
    if (t + 2 < KT) STAGE_A1(t + 2);
    if (t + 1 < KT) {
      if (t + 2 < KT)
        asm volatile("s_waitcnt vmcnt(2)" ::: "memory");  // ADMA(t+1)+L retired; ADMA(t+2) in flight
      else
        asm volatile("s_waitcnt vmcnt(0)" ::: "memory");  // tail
      __builtin_amdgcn_sched_barrier(0);
      if (t_ < 256) WRITE_B1(t + 1);
    }
    LGKM0_BAR();
    MFMA_OCT(1, 1);
    __builtin_amdgcn_s_barrier();
  }
#undef STAGE_A1
#undef WRITE_B1
#undef MFMA_OCT
#undef LGKM0_BAR

  // epilogue: D row = lhi*4+reg, col = l15 (verified C/D layout); bf16 out
#pragma unroll
  for (int mf = 0; mf < 8; mf++) {
#pragma unroll
    for (int nf = 0; nf < 4; nf++) {
#pragma unroll
      for (int rg = 0; rg < 4; rg++) {
        float v = acc[mf][nf][rg];
        int grow = mt * 256 + wm * 128 + mf * 16 + lhi * 4 + rg;
        int gcol = nt * 256 + wn * 64 + nf * 16 + l15;
        size_t off = ((size_t)e * CAP + grow) * NN + gcol;
        if constexpr (SILU) v = v / (1.0f + __expf(-v));  // silu
        Cout[off] = f2bf(v);
      }
    }
  }
}

// ------------------------------------------------------------ grouped GEMM
// R15-verbatim (best verified; used for GEMM2): 256x256/BK=64/8-wave 4-phase.
template <int K, int NN, bool SILU>
__global__ __launch_bounds__(512, 2) void k_gemm(const u16* __restrict__ A,
                                                 const float* __restrict__ Wf,
                                                 u16* __restrict__ Cout) {
  constexpr int MT = CAP / 256;        // 2
  constexpr int NT = NN / 256;
  constexpr int NWG = NEXP * MT * NT;  // %8 == 0
  constexpr int Q = NWG / 8;
  constexpr int KT = K / 64;           // 16 for K=1024
  int wg = (blockIdx.x % 8) * Q + blockIdx.x / 8;  // XCD chunked swizzle
  int e = wg / (MT * NT);
  int rm = wg % (MT * NT);
  int mt = rm / NT, nt = rm % NT;

  const u16* Ab = A + ((size_t)e * CAP + (size_t)mt * 256) * K;

  __shared__ __align__(16) char smc[131072];

  int t_ = threadIdx.x;
  int lane = t_ & 63, wv = t_ >> 6;
  int wm = wv >> 2, wn = wv & 3;
  int l15 = lane & 15, lhi = lane >> 4;

  int srow = t_ >> 3;
  int gchunk = (t_ & 7) ^ (srow & 7);
  const u16* gA = Ab + (size_t)srow * K + gchunk * 8;
#define STAGE_HALF_A(tn, j)                                                  \
  do {                                                                       \
    char* d_ = smc + ((tn) & 1) * 32768 + (j) * 16384 + wv * 1024;           \
    const u16* s_ = gA + (size_t)((j) * 128) * K + (tn) * 64;                \
    GLOAD_LDS16(s_, d_);                                                     \
    GLOAD_LDS16(s_ + (size_t)64 * K, d_ + 8192);                             \
  } while (0)

  int kunit = t_ >> 6;
  int nunit = t_ & 63;
  const float* gWb = Wf + (size_t)e * K * NN + (size_t)(kunit * 8) * NN +
                     (size_t)nt * 256 + nunit * 4;
  int wbo[4];
#pragma unroll
  for (int i = 0; i < 4; i++) {
    int n = nunit * 4 + i;
    int S = (n ^ (n >> 3)) & 7;
    wbo[i] = n * 128 + ((kunit ^ S) << 4);
  }

  f32x4 acc[8][4];
#pragma unroll
  for (int i = 0; i < 8; i++)
#pragma unroll
    for (int j = 0; j < 4; j++) {
      f32x4 z = {0.f, 0.f, 0.f, 0.f};
      acc[i][j] = z;
    }
  bf16x8 a[4][2], b[4][2];

  int aof0 = (wm * 128 + l15) * 128 + ((lhi ^ (l15 & 7)) << 4);
  int aof1 = (wm * 128 + l15) * 128 + (((4 + lhi) ^ (l15 & 7)) << 4);
  int boff[4][2];
#pragma unroll
  for (int nf = 0; nf < 4; nf++) {
    int r = wn * 64 + nf * 16 + l15;
    int Sr = (r ^ (r >> 3)) & 7;
    boff[nf][0] = r * 128 + ((lhi ^ Sr) << 4);
    boff[nf][1] = r * 128 + (((4 + lhi) ^ Sr) << 4);
  }

#define LGKM0_BAR()                                                          \
  do {                                                                       \
    asm volatile("s_waitcnt lgkmcnt(0)" ::: "memory");                       \
    __builtin_amdgcn_sched_barrier(0);                                       \
    __builtin_amdgcn_s_barrier();                                            \
  } while (0)

#define MFMA_QUAD(mh, nh)                                                    \
  do {                                                                       \
    __builtin_amdgcn_s_setprio(1);                                           \
    _Pragma("unroll") for (int mf = 0; mf < 4; mf++)                         \
        _Pragma("unroll") for (int nf = 0; nf < 2; nf++)                     \
            _Pragma("unroll") for (int kk = 0; kk < 2; kk++)                 \
                acc[(mh)*4 + mf][(nh)*2 + nf] = __builtin_amdgcn_mfma_f32_16x16x32_bf16( \
                    a[mf][kk], b[(nh)*2 + nf][kk], acc[(mh)*4 + mf][(nh)*2 + nf], 0, 0, 0); \
    __builtin_amdgcn_s_setprio(0);                                           \
  } while (0)

  STAGE_HALF_A(0, 0); STAGE_HALF_A(0, 1);
  if (KT > 1) { STAGE_HALF_A(1, 0); STAGE_HALF_A(1, 1); }
  {
    float4 P[8];
#pragma unroll
    for (int j = 0; j < 8; j++)
      P[j] = *reinterpret_cast<const float4*>(gWb + (size_t)j * NN);
    char* wB = smc + 65536;
#pragma unroll
    for (int i = 0; i < 4; i++) {
      uint4 v;
      v.x = pkbf(P[0][i], P[1][i]); v.y = pkbf(P[2][i], P[3][i]);
      v.z = pkbf(P[4][i], P[5][i]); v.w = pkbf(P[6][i], P[7][i]);
      *reinterpret_cast<uint4*>(wB + wbo[i]) = v;
    }
  }
  asm volatile("s_waitcnt vmcnt(0)" ::: "memory");
  LGKM0_BAR();

  for (int t = 0; t < KT; t++) {
    const char* pA = smc + (t & 1) * 32768;
    const char* pB = smc + 65536 + (t & 1) * 32768;
    char* wB = smc + 65536 + ((t + 1) & 1) * 32768;
    float4 L0, L1, L2, L3, L4, L5, L6, L7;

#pragma unroll
    for (int mf = 0; mf < 4; mf++) {
      a[mf][0] = *reinterpret_cast<const bf16x8*>(pA + aof0 + mf * 2048);
      a[mf][1] = *reinterpret_cast<const bf16x8*>(pA + aof1 + mf * 2048);
    }
#pragma unroll
    for (int nf = 0; nf < 2; nf++) {
      b[nf][0] = *reinterpret_cast<const bf16x8*>(pB + boff[nf][0]);
      b[nf][1] = *reinterpret_cast<const bf16x8*>(pB + boff[nf][1]);
    }
    if (t + 1 < KT) {
      const float* g = gWb + (size_t)(t + 1) * 64 * NN;
      L0 = *reinterpret_cast<const float4*>(g);
      L1 = *reinterpret_cast<const float4*>(g + (size_t)1 * NN);
      L2 = *reinterpret_cast<const float4*>(g + (size_t)2 * NN);
      L3 = *reinterpret_cast<const float4*>(g + (size_t)3 * NN);
    }
    LGKM0_BAR();
    MFMA_QUAD(0, 0);
    __builtin_amdgcn_s_barrier();

#pragma unroll
    for (int nf = 0; nf < 2; nf++) {
      b[2 + nf][0] = *reinterpret_cast<const bf16x8*>(pB + boff[2 + nf][0]);
      b[2 + nf][1] = *reinterpret_cast<const bf16x8*>(pB + boff[2 + nf][1]);
    }
    if (t + 1 < KT) {
      const float* g = gWb + (size_t)(t + 1) * 64 * NN;
      L4 = *reinterpret_cast<const float4*>(g + (size_t)4 * NN);
      L5 = *reinterpret_cast<const float4*>(g + (size_t)5 * NN);
      L6 = *reinterpret_cast<const float4*>(g + (size_t)6 * NN);
      L7 = *reinterpret_cast<const float4*>(g + (size_t)7 * NN);
    }
    LGKM0_BAR();
    MFMA_QUAD(0, 1);
    __builtin_amdgcn_s_barrier();

#pragma unroll
    for (int mf = 0; mf < 4; mf++) {
      a[mf][0] = *reinterpret_cast<const bf16x8*>(pA + aof0 + (4 + mf) * 2048);
      a[mf][1] = *reinterpret_cast<const bf16x8*>(pA + aof1 + (4 + mf) * 2048);
    }
    LGKM0_BAR();
    MFMA_QUAD(1, 0);
    __builtin_amdgcn_s_barrier();

    if (t + 2 < KT) { STAGE_HALF_A(t + 2, 0); STAGE_HALF_A(t + 2, 1); }
    if (t + 1 < KT) {
      if (t + 2 < KT)
        asm volatile("s_waitcnt vmcnt(4)" ::: "memory");
      else
        asm volatile("s_waitcnt vmcnt(0)" ::: "memory");
      __builtin_amdgcn_sched_barrier(0);
#pragma unroll
      for (int i = 0; i < 4; i++) {
        uint4 v;
        v.x = pkbf(L0[i], L1[i]); v.y = pkbf(L2[i], L3[i]);
        v.z = pkbf(L4[i], L5[i]); v.w = pkbf(L6[i], L7[i]);
        *reinterpret_cast<uint4*>(wB + wbo[i]) = v;
      }
    }
    LGKM0_BAR();
    MFMA_QUAD(1, 1);
    __builtin_amdgcn_s_barrier();
  }
#undef STAGE_HALF_A
#undef MFMA_QUAD
#undef LGKM0_BAR

#pragma unroll
  for (int mf = 0; mf < 8; mf++) {
#pragma unroll
    for (int nf = 0; nf < 4; nf++) {
#pragma unroll
      for (int rg = 0; rg < 4; rg++) {
        float v = acc[mf][nf][rg];
        int grow = mt * 256 + wm * 128 + mf * 16 + lhi * 4 + rg;
        int gcol = nt * 256 + wn * 64 + nf * 16 + l15;
        size_t off = ((size_t)e * CAP + grow) * NN + gcol;
        if constexpr (SILU) v = v / (1.0f + __expf(-v));  // silu
        Cout[off] = f2bf(v);
      }
    }
  }
}

// ------------------------------------------- weighted combine (no atomics)
__global__ void k_combine(const u16* __restrict__ yws, const int* __restrict__ slot_pos,
                          const float* __restrict__ w, float* __restrict__ out) {
  int tk = blockIdx.x * 4 + (threadIdx.x >> 6);
  int lane = threadIdx.x & 63;
  int p0 = slot_pos[2 * tk], p1 = slot_pos[2 * tk + 1];
  float w0 = w[2 * tk], w1 = w[2 * tk + 1];
  uint4 ua = reinterpret_cast<const uint4*>(yws + (size_t)p0 * HID)[lane];
  uint4 ub = reinterpret_cast<const uint4*>(yws + (size_t)p1 * HID)[lane];
  float4 o0, o1;
  o0.x = w0 * bf2f(ua.x & 0xffffu) + w1 * bf2f(ub.x & 0xffffu);
  o0.y = w0 * bf2f(ua.x >> 16) + w1 * bf2f(ub.x >> 16);
  o0.z = w0 * bf2f(ua.y & 0xffffu) + w1 * bf2f(ub.y & 0xffffu);
  o0.w = w0 * bf2f(ua.y >> 16) + w1 * bf2f(ub.y >> 16);
  o1.x = w0 * bf2f(ua.z & 0xffffu) + w1 * bf2f(ub.z & 0xffffu);
  o1.y = w0 * bf2f(ua.z >> 16) + w1 * bf2f(ub.z >> 16);
  o1.z = w0 * bf2f(ua.w & 0xffffu) + w1 * bf2f(ub.w & 0xffffu);
  o1.w = w0 * bf2f(ua.w >> 16) + w1 * bf2f(ub.w >> 16);
  float4* dst = reinterpret_cast<float4*>(out + (size_t)tk * HID + lane * 8);
  dst[0] = o0;
  dst[1] = o1;
}

// ---------------------------------------------------------------- launcher
extern "C" void kernel_launch(void* const* d_in, const int* in_sizes, int n_in,
                              void* d_out, int out_size, void* d_ws, size_t ws_size,
                              hipStream_t stream) {
  const float* hs = (const float*)d_in[0];
  const float* wts = (const float*)d_in[1];
  const int* ids = (const int*)d_in[2];
  const float* W1 = (const float*)d_in[3];
  const float* W2 = (const float*)d_in[4];
  float* out = (float*)d_out;

  char* ws = (char*)d_ws;
  size_t o = 0;
  int* cnt = (int*)(ws + o);       o += 1024;
  int* slot_pos = (int*)(ws + o);  o += (size_t)NASSIGN * 4;
  int* tok_of = (int*)(ws + o);    o += (size_t)NASSIGN * 4;
  o = (o + 255) & ~(size_t)255;
  u16* Xg = (u16*)(ws + o);        o += (size_t)NASSIGN * HID * 2;      // 32 MB
  u16* hid = (u16*)(ws + o);       o += (size_t)NASSIGN * FFN * 2;      // 64 MB
  u16* yws = (u16*)(ws + o);       o += (size_t)NASSIGN * HID * 2;      // 32 MB

  hipMemsetAsync(cnt, 0, NEXP * sizeof(int), stream);
  k_route<<<(NASSIGN + 255) / 256, 256, 0, stream>>>(ids, cnt, tok_of, slot_pos);
  k_gather<<<NASSIGN / 4, 256, 0, stream>>>(hs, tok_of, Xg);
  k_gemm1<HID, FFN, true><<<NEXP * (CAP / 256) * (FFN / 256), 512, 0, stream>>>(Xg, W1, hid);
  k_gemm<FFN, HID, false><<<NEXP * (CAP / 256) * (HID / 256), 512, 0, stream>>>(hid, W2, yws);
  k_combine<<<B_TOK / 4, 256, 0, stream>>>(yws, slot_pos, wts, out);
}

// Round 17
// 213.767 us; speedup vs baseline: 4.2145x; 4.2145x over previous
//
#include <hip/hip_runtime.h>
#include <hip/hip_bf16.h>

#define B_TOK 16384
#define TOPK 2
#define NEXP 64
#define HID 512
#define FFN 1024
#define NASSIGN (B_TOK * TOPK)   // 32768
#define CAP (NASSIGN / NEXP)     // 512 assignments per expert (balanced)

typedef unsigned short u16;
typedef __bf16 bf16_t;
typedef bf16_t bf16x8 __attribute__((ext_vector_type(8)));
typedef float f32x4 __attribute__((ext_vector_type(4)));

// native cvt: compiler emits v_cvt_pk_bf16_f32 (RTNE)
__device__ __forceinline__ unsigned pkbf(float a, float b) {
  union { bf16_t h[2]; unsigned u; } v;
  v.h[0] = (bf16_t)a; v.h[1] = (bf16_t)b;
  return v.u;
}
__device__ __forceinline__ u16 f2bf(float f) {
  union { bf16_t h; u16 u; } v; v.h = (bf16_t)f; return v.u;
}
__device__ __forceinline__ float bf2f(unsigned u16v) {
  union { unsigned u; float f; } v; v.u = u16v << 16; return v.f;
}

#define GLOAD_LDS16(g, l)                                                     \
  __builtin_amdgcn_global_load_lds((const __attribute__((address_space(1))) void*)(g), \
                                   (__attribute__((address_space(3))) void*)(l), 16, 0, 0)

// ---------------------------------------------------------------- routing
__global__ void k_route(const int* __restrict__ ids, int* __restrict__ cnt,
                        int* __restrict__ tok_of, int* __restrict__ slot_pos) {
  int n = blockIdx.x * blockDim.x + threadIdx.x;
  if (n >= NASSIGN) return;
  int e = ids[n];
  int r = atomicAdd(&cnt[e], 1);
  int p = e * CAP + r;
  tok_of[p] = n >> 1;       // token index for sorted slot p
  slot_pos[n] = p;          // inverse map: assignment n -> sorted slot
}

// ------------------------------------------------- gather + fp32->bf16 cast
__global__ void k_gather(const float* __restrict__ hs, const int* __restrict__ tok_of,
                         u16* __restrict__ Xg) {
  int p = blockIdx.x * 4 + (threadIdx.x >> 6);
  int lane = threadIdx.x & 63;
  const float4* src = reinterpret_cast<const float4*>(hs + (size_t)tok_of[p] * HID);
  uint2* dst = reinterpret_cast<uint2*>(Xg + (size_t)p * HID);
#pragma unroll
  for (int i = 0; i < 2; i++) {
    float4 v = src[i * 64 + lane];
    uint2 o;
    o.x = pkbf(v.x, v.y);
    o.y = pkbf(v.z, v.w);
    dst[i * 64 + lane] = o;
  }
}

// ------------------------------------------------------------ grouped GEMM
// R15 skeleton (best verified) with ONE change: m201 phase order
// [mem issue] -> barrier -> lgkmcnt(0) -> MFMA  (was: lgkm0 -> barrier ->
// MFMA).  Each wave now waits only its OWN lgkm counter after the barrier;
// its ds_read latency overlaps other waves' MFMA instead of serializing at
// the barrier.  Safety: every phase's lgkm0 precedes its MFMA, which
// precedes the trailing barrier -- so by each trailing barrier, all waves'
// ds_reads AND ds_writes (lgkm-tracked) of that phase are complete;
// cross-wave buffer reuse (ph3 B-writes -> next ph0 reads; ph2 a47 reads ->
// ph3 A-DMA into current slot) is therefore race-free.  vmcnt discipline
// unchanged (counted vmcnt(4) at ph3; never 0 mid-loop).  Prologue keeps
// lgkm0-before-barrier (no MFMA follows it there).
template <int K, int NN, bool SILU>
__global__ __launch_bounds__(512, 2) void k_gemm(const u16* __restrict__ A,
                                                 const float* __restrict__ Wf,
                                                 u16* __restrict__ Cout) {
  constexpr int MT = CAP / 256;        // 2
  constexpr int NT = NN / 256;
  constexpr int NWG = NEXP * MT * NT;  // %8 == 0
  constexpr int Q = NWG / 8;
  constexpr int KT = K / 64;           // 8 or 16
  int wg = (blockIdx.x % 8) * Q + blockIdx.x / 8;  // XCD chunked swizzle
  int e = wg / (MT * NT);
  int rm = wg % (MT * NT);
  int mt = rm / NT, nt = rm % NT;

  const u16* Ab = A + ((size_t)e * CAP + (size_t)mt * 256) * K;

  // LDS: A dbuf 2x32KB at 0; B dbuf 2x32KB at 65536. 128KB.
  __shared__ __align__(16) char smc[131072];

  int t_ = threadIdx.x;
  int lane = t_ & 63, wv = t_ >> 6;
  int wm = wv >> 2, wn = wv & 3;        // 2x4 wave grid; wave out = 128x64
  int l15 = lane & 15, lhi = lane >> 4;

  // ---- A staging (global_load_lds): row t_>>3, chunk pos t_&7, src chunk ^row&7
  int srow = t_ >> 3;
  int gchunk = (t_ & 7) ^ (srow & 7);
  const u16* gA = Ab + (size_t)srow * K + gchunk * 8;
#define STAGE_HALF_A(tn, j)                                                  \
  do {                                                                       \
    char* d_ = smc + ((tn) & 1) * 32768 + (j) * 16384 + wv * 1024;           \
    const u16* s_ = gA + (size_t)((j) * 128) * K + (tn) * 64;                \
    GLOAD_LDS16(s_, d_);                                                     \
    GLOAD_LDS16(s_ + (size_t)64 * K, d_ + 8192);                             \
  } while (0)

  // ---- B staging (reg-staged transpose+cvt from fp32 W[k][n])
  int kunit = t_ >> 6;                  // 0..7
  int nunit = t_ & 63;                  // 0..63
  const float* gWb = Wf + (size_t)e * K * NN + (size_t)(kunit * 8) * NN +
                     (size_t)nt * 256 + nunit * 4;
  int wbo[4];                           // byte offsets of the 4 write slots
#pragma unroll
  for (int i = 0; i < 4; i++) {
    int n = nunit * 4 + i;
    int S = (n ^ (n >> 3)) & 7;
    wbo[i] = n * 128 + ((kunit ^ S) << 4);
  }

  f32x4 acc[8][4];
#pragma unroll
  for (int i = 0; i < 8; i++)
#pragma unroll
    for (int j = 0; j < 4; j++) {
      f32x4 z = {0.f, 0.f, 0.f, 0.f};
      acc[i][j] = z;
    }
  bf16x8 a[4][2], b[4][2];

  // ---- fragment read offsets
  int aof0 = (wm * 128 + l15) * 128 + ((lhi ^ (l15 & 7)) << 4);
  int aof1 = (wm * 128 + l15) * 128 + (((4 + lhi) ^ (l15 & 7)) << 4);
  int boff[4][2];
#pragma unroll
  for (int nf = 0; nf < 4; nf++) {
    int r = wn * 64 + nf * 16 + l15;
    int Sr = (r ^ (r >> 3)) & 7;
    boff[nf][0] = r * 128 + ((lhi ^ Sr) << 4);
    boff[nf][1] = r * 128 + (((4 + lhi) ^ Sr) << 4);
  }

// m201 order: barrier first, then own-counter wait, then MFMA.
#define BAR_THEN_LGKM0()                                                     \
  do {                                                                       \
    __builtin_amdgcn_sched_barrier(0);                                       \
    __builtin_amdgcn_s_barrier();                                            \
    asm volatile("s_waitcnt lgkmcnt(0)" ::: "memory");                       \
    __builtin_amdgcn_sched_barrier(0);                                       \
  } while (0)

#define MFMA_QUAD(mh, nh)                                                    \
  do {                                                                       \
    __builtin_amdgcn_s_setprio(1);                                           \
    _Pragma("unroll") for (int mf = 0; mf < 4; mf++)                         \
        _Pragma("unroll") for (int nf = 0; nf < 2; nf++)                     \
            _Pragma("unroll") for (int kk = 0; kk < 2; kk++)                 \
                acc[(mh)*4 + mf][(nh)*2 + nf] = __builtin_amdgcn_mfma_f32_16x16x32_bf16( \
                    a[mf][kk], b[(nh)*2 + nf][kk], acc[(mh)*4 + mf][(nh)*2 + nf], 0, 0, 0); \
    __builtin_amdgcn_s_setprio(0);                                           \
  } while (0)

  // ---- prologue: A(0), A(1) via DMA; B(0) reg-staged into slot 0
  // (keeps lgkm0-BEFORE-barrier: writes must drain before any ph0 read)
  STAGE_HALF_A(0, 0); STAGE_HALF_A(0, 1);
  if (KT > 1) { STAGE_HALF_A(1, 0); STAGE_HALF_A(1, 1); }
  {
    float4 P[8];
#pragma unroll
    for (int j = 0; j < 8; j++)
      P[j] = *reinterpret_cast<const float4*>(gWb + (size_t)j * NN);
    char* wB = smc + 65536;  // slot 0
#pragma unroll
    for (int i = 0; i < 4; i++) {
      uint4 v;
      v.x = pkbf(P[0][i], P[1][i]); v.y = pkbf(P[2][i], P[3][i]);
      v.z = pkbf(P[4][i], P[5][i]); v.w = pkbf(P[6][i], P[7][i]);
      *reinterpret_cast<uint4*>(wB + wbo[i]) = v;
    }
  }
  asm volatile("s_waitcnt vmcnt(0) lgkmcnt(0)" ::: "memory");  // A(0),A(1) resident; B(0) written
  __builtin_amdgcn_sched_barrier(0);
  __builtin_amdgcn_s_barrier();

  for (int t = 0; t < KT; t++) {
    const char* pA = smc + (t & 1) * 32768;
    const char* pB = smc + 65536 + (t & 1) * 32768;
    char* wB = smc + 65536 + ((t + 1) & 1) * 32768;
    float4 L0, L1, L2, L3, L4, L5, L6, L7;

    // ---------------- phase 0: frags a03+b01; issue L0..3(t+1)
#pragma unroll
    for (int mf = 0; mf < 4; mf++) {
      a[mf][0] = *reinterpret_cast<const bf16x8*>(pA + aof0 + mf * 2048);
      a[mf][1] = *reinterpret_cast<const bf16x8*>(pA + aof1 + mf * 2048);
    }
#pragma unroll
    for (int nf = 0; nf < 2; nf++) {
      b[nf][0] = *reinterpret_cast<const bf16x8*>(pB + boff[nf][0]);
      b[nf][1] = *reinterpret_cast<const bf16x8*>(pB + boff[nf][1]);
    }
    if (t + 1 < KT) {
      const float* g = gWb + (size_t)(t + 1) * 64 * NN;
      L0 = *reinterpret_cast<const float4*>(g);
      L1 = *reinterpret_cast<const float4*>(g + (size_t)1 * NN);
      L2 = *reinterpret_cast<const float4*>(g + (size_t)2 * NN);
      L3 = *reinterpret_cast<const float4*>(g + (size_t)3 * NN);
    }
    BAR_THEN_LGKM0();
    MFMA_QUAD(0, 0);
    __builtin_amdgcn_s_barrier();

    // ---------------- phase 1: frags b23; issue L4..7(t+1)
#pragma unroll
    for (int nf = 0; nf < 2; nf++) {
      b[2 + nf][0] = *reinterpret_cast<const bf16x8*>(pB + boff[2 + nf][0]);
      b[2 + nf][1] = *reinterpret_cast<const bf16x8*>(pB + boff[2 + nf][1]);
    }
    if (t + 1 < KT) {
      const float* g = gWb + (size_t)(t + 1) * 64 * NN;
      L4 = *reinterpret_cast<const float4*>(g + (size_t)4 * NN);
      L5 = *reinterpret_cast<const float4*>(g + (size_t)5 * NN);
      L6 = *reinterpret_cast<const float4*>(g + (size_t)6 * NN);
      L7 = *reinterpret_cast<const float4*>(g + (size_t)7 * NN);
    }
    BAR_THEN_LGKM0();
    MFMA_QUAD(0, 1);
    __builtin_amdgcn_s_barrier();

    // ---------------- phase 2: frags a47 (lgkm0 precedes MFMA(1,0), so all
    // a-reads complete before this phase's trailing barrier)
#pragma unroll
    for (int mf = 0; mf < 4; mf++) {
      a[mf][0] = *reinterpret_cast<const bf16x8*>(pA + aof0 + (4 + mf) * 2048);
      a[mf][1] = *reinterpret_cast<const bf16x8*>(pA + aof1 + (4 + mf) * 2048);
    }
    BAR_THEN_LGKM0();
    MFMA_QUAD(1, 0);
    __builtin_amdgcn_s_barrier();

    // ---------------- phase 3: A(t+2) DMA; counted vmcnt; uint4 B-writes
    if (t + 2 < KT) { STAGE_HALF_A(t + 2, 0); STAGE_HALF_A(t + 2, 1); }
    if (t + 1 < KT) {
      if (t + 2 < KT)
        asm volatile("s_waitcnt vmcnt(4)" ::: "memory");  // L0..7 retired; ADMA in flight
      else
        asm volatile("s_waitcnt vmcnt(0)" ::: "memory");  // tail
      __builtin_amdgcn_sched_barrier(0);
#pragma unroll
      for (int i = 0; i < 4; i++) {
        uint4 v;
        v.x = pkbf(L0[i], L1[i]); v.y = pkbf(L2[i], L3[i]);
        v.z = pkbf(L4[i], L5[i]); v.w = pkbf(L6[i], L7[i]);
        *reinterpret_cast<uint4*>(wB + wbo[i]) = v;
      }
    }
    BAR_THEN_LGKM0();   // lgkm0 drains my B-writes before MFMA(1,1) -> before trailing barrier
    MFMA_QUAD(1, 1);
    __builtin_amdgcn_s_barrier();
  }
#undef STAGE_HALF_A
#undef MFMA_QUAD
#undef BAR_THEN_LGKM0

  // epilogue: D row = lhi*4+reg, col = l15 (verified C/D layout); bf16 out
#pragma unroll
  for (int mf = 0; mf < 8; mf++) {
#pragma unroll
    for (int nf = 0; nf < 4; nf++) {
#pragma unroll
      for (int rg = 0; rg < 4; rg++) {
        float v = acc[mf][nf][rg];
        int grow = mt * 256 + wm * 128 + mf * 16 + lhi * 4 + rg;
        int gcol = nt * 256 + wn * 64 + nf * 16 + l15;
        size_t off = ((size_t)e * CAP + grow) * NN + gcol;
        if constexpr (SILU) v = v / (1.0f + __expf(-v));  // silu
        Cout[off] = f2bf(v);
      }
    }
  }
}

// ------------------------------------------- weighted combine (no atomics)
// wave per token: lane reads uint4 (8 bf16) per slot row, writes 2 float4.
__global__ void k_combine(const u16* __restrict__ yws, const int* __restrict__ slot_pos,
                          const float* __restrict__ w, float* __restrict__ out) {
  int tk = blockIdx.x * 4 + (threadIdx.x >> 6);
  int lane = threadIdx.x & 63;
  int p0 = slot_pos[2 * tk], p1 = slot_pos[2 * tk + 1];
  float w0 = w[2 * tk], w1 = w[2 * tk + 1];
  uint4 ua = reinterpret_cast<const uint4*>(yws + (size_t)p0 * HID)[lane];
  uint4 ub = reinterpret_cast<const uint4*>(yws + (size_t)p1 * HID)[lane];
  float4 o0, o1;
  o0.x = w0 * bf2f(ua.x & 0xffffu) + w1 * bf2f(ub.x & 0xffffu);
  o0.y = w0 * bf2f(ua.x >> 16) + w1 * bf2f(ub.x >> 16);
  o0.z = w0 * bf2f(ua.y & 0xffffu) + w1 * bf2f(ub.y & 0xffffu);
  o0.w = w0 * bf2f(ua.y >> 16) + w1 * bf2f(ub.y >> 16);
  o1.x = w0 * bf2f(ua.z & 0xffffu) + w1 * bf2f(ub.z & 0xffffu);
  o1.y = w0 * bf2f(ua.z >> 16) + w1 * bf2f(ub.z >> 16);
  o1.z = w0 * bf2f(ua.w & 0xffffu) + w1 * bf2f(ub.w & 0xffffu);
  o1.w = w0 * bf2f(ua.w >> 16) + w1 * bf2f(ub.w >> 16);
  float4* dst = reinterpret_cast<float4*>(out + (size_t)tk * HID + lane * 8);
  dst[0] = o0;
  dst[1] = o1;
}

// ---------------------------------------------------------------- launcher
extern "C" void kernel_launch(void* const* d_in, const int* in_sizes, int n_in,
                              void* d_out, int out_size, void* d_ws, size_t ws_size,
                              hipStream_t stream) {
  const float* hs = (const float*)d_in[0];
  const float* wts = (const float*)d_in[1];
  const int* ids = (const int*)d_in[2];
  const float* W1 = (const float*)d_in[3];
  const float* W2 = (const float*)d_in[4];
  float* out = (float*)d_out;

  char* ws = (char*)d_ws;
  size_t o = 0;
  int* cnt = (int*)(ws + o);       o += 1024;
  int* slot_pos = (int*)(ws + o);  o += (size_t)NASSIGN * 4;
  int* tok_of = (int*)(ws + o);    o += (size_t)NASSIGN * 4;
  o = (o + 255) & ~(size_t)255;
  u16* Xg = (u16*)(ws + o);        o += (size_t)NASSIGN * HID * 2;      // 32 MB
  u16* hid = (u16*)(ws + o);       o += (size_t)NASSIGN * FFN * 2;      // 64 MB
  u16* yws = (u16*)(ws + o);       o += (size_t)NASSIGN * HID * 2;      // 32 MB

  hipMemsetAsync(cnt, 0, NEXP * sizeof(int), stream);
  k_route<<<(NASSIGN + 255) / 256, 256, 0, stream>>>(ids, cnt, tok_of, slot_pos);
  k_gather<<<NASSIGN / 4, 256, 0, stream>>>(hs, tok_of, Xg);
  k_gemm<HID, FFN, true><<<NEXP * (CAP / 256) * (FFN / 256), 512, 0, stream>>>(Xg, W1, hid);
  k_gemm<FFN, HID, false><<<NEXP * (CAP / 256) * (HID / 256), 512, 0, stream>>>(hid, W2, yws);
  k_combine<<<B_TOK / 4, 256, 0, stream>>>(yws, slot_pos, wts, out);
}

// Round 18
// 206.382 us; speedup vs baseline: 4.3653x; 1.0358x over previous
//
#include <hip/hip_runtime.h>
#include <hip/hip_bf16.h>

#define B_TOK 16384
#define TOPK 2
#define NEXP 64
#define HID 512
#define FFN 1024
#define NASSIGN (B_TOK * TOPK)   // 32768
#define CAP (NASSIGN / NEXP)     // 512 assignments per expert (balanced)

typedef unsigned short u16;
typedef __bf16 bf16_t;
typedef bf16_t bf16x8 __attribute__((ext_vector_type(8)));
typedef float f32x4 __attribute__((ext_vector_type(4)));

// native cvt: compiler emits v_cvt_pk_bf16_f32 (RTNE)
__device__ __forceinline__ unsigned pkbf(float a, float b) {
  union { bf16_t h[2]; unsigned u; } v;
  v.h[0] = (bf16_t)a; v.h[1] = (bf16_t)b;
  return v.u;
}
__device__ __forceinline__ u16 f2bf(float f) {
  union { bf16_t h; u16 u; } v; v.h = (bf16_t)f; return v.u;
}
__device__ __forceinline__ float bf2f(unsigned u16v) {
  union { unsigned u; float f; } v; v.u = u16v << 16; return v.f;
}

#define GLOAD_LDS16(g, l)                                                     \
  __builtin_amdgcn_global_load_lds((const __attribute__((address_space(1))) void*)(g), \
                                   (__attribute__((address_space(3))) void*)(l), 16, 0, 0)

// ---------------------------------------------------------------- routing
__global__ void k_route(const int* __restrict__ ids, int* __restrict__ cnt,
                        int* __restrict__ tok_of, int* __restrict__ slot_pos) {
  int n = blockIdx.x * blockDim.x + threadIdx.x;
  if (n >= NASSIGN) return;
  int e = ids[n];
  int r = atomicAdd(&cnt[e], 1);
  int p = e * CAP + r;
  tok_of[p] = n >> 1;       // token index for sorted slot p
  slot_pos[n] = p;          // inverse map: assignment n -> sorted slot
}

// ------------------------------------------------- gather + fp32->bf16 cast
__global__ void k_gather(const float* __restrict__ hs, const int* __restrict__ tok_of,
                         u16* __restrict__ Xg) {
  int p = blockIdx.x * 4 + (threadIdx.x >> 6);
  int lane = threadIdx.x & 63;
  const float4* src = reinterpret_cast<const float4*>(hs + (size_t)tok_of[p] * HID);
  uint2* dst = reinterpret_cast<uint2*>(Xg + (size_t)p * HID);
#pragma unroll
  for (int i = 0; i < 2; i++) {
    float4 v = src[i * 64 + lane];
    uint2 o;
    o.x = pkbf(v.x, v.y);
    o.y = pkbf(v.z, v.w);
    dst[i * 64 + lane] = o;
  }
}

// ------------------------------------------------------------ grouped GEMM
// R15 skeleton with the K-loop collapsed to the m248-style minimal 2-phase:
// ONE barrier per K-tile (was 8).  Per tile t:
//   LOAD_L(t+1) [8 fp32x4] ; STAGE_A(t+1) -> OPPOSITE A-slot [4 DMA]
//   read a03 + b0123 (16 ds_read_b128) ; lgkm0 ; 32 MFMA
//   read a47 (8, reusing a[] regs)     ; lgkm0 ; 32 MFMA
//   vmcnt(4)  [queue = 8 L then 4 ADMA -> retires L exactly, ADMA in flight]
//   WRITE_B(t+1) -> OPPOSITE B-slot (4x uint4 swizzled)
//   vmcnt(0)+lgkm0 ; s_barrier        [ADMA had a full tile of cover]
// Safety: all ds_reads/writes of tile t drain (per-wave lgkm0) before the
// single trailing barrier; opp-slot readers (tile t-1) drained before the
// previous barrier; so DMA/writes into opp never race in-flight reads.
// Swizzles (both-sides, rule #21): A chunk c -> c^(row&7) (pre-swizzled
// global source, linear gload_lds dest); B chunk c -> c^S(n),
// S(n)=(n^(n>>3))&7 (reg-staged writes), matching ds_read addresses.
template <int K, int NN, bool SILU>
__global__ __launch_bounds__(512, 2) void k_gemm(const u16* __restrict__ A,
                                                 const float* __restrict__ Wf,
                                                 u16* __restrict__ Cout) {
  constexpr int MT = CAP / 256;        // 2
  constexpr int NT = NN / 256;
  constexpr int NWG = NEXP * MT * NT;  // %8 == 0
  constexpr int Q = NWG / 8;
  constexpr int KT = K / 64;           // 8 or 16
  int wg = (blockIdx.x % 8) * Q + blockIdx.x / 8;  // XCD chunked swizzle
  int e = wg / (MT * NT);
  int rm = wg % (MT * NT);
  int mt = rm / NT, nt = rm % NT;

  const u16* Ab = A + ((size_t)e * CAP + (size_t)mt * 256) * K;

  // LDS: A dbuf 2x32KB at 0; B dbuf 2x32KB at 65536. 128KB.
  __shared__ __align__(16) char smc[131072];

  int t_ = threadIdx.x;
  int lane = t_ & 63, wv = t_ >> 6;
  int wm = wv >> 2, wn = wv & 3;        // 2x4 wave grid; wave out = 128x64
  int l15 = lane & 15, lhi = lane >> 4;

  // ---- A staging (global_load_lds): row t_>>3, chunk pos t_&7, src chunk ^row&7
  int srow = t_ >> 3;
  int gchunk = (t_ & 7) ^ (srow & 7);
  const u16* gA = Ab + (size_t)srow * K + gchunk * 8;
#define STAGE_HALF_A(tn, j)                                                  \
  do {                                                                       \
    char* d_ = smc + ((tn) & 1) * 32768 + (j) * 16384 + wv * 1024;           \
    const u16* s_ = gA + (size_t)((j) * 128) * K + (tn) * 64;                \
    GLOAD_LDS16(s_, d_);                                                     \
    GLOAD_LDS16(s_ + (size_t)64 * K, d_ + 8192);                             \
  } while (0)

  // ---- B staging (reg-staged transpose+cvt from fp32 W[k][n])
  int kunit = t_ >> 6;                  // 0..7
  int nunit = t_ & 63;                  // 0..63
  const float* gWb = Wf + (size_t)e * K * NN + (size_t)(kunit * 8) * NN +
                     (size_t)nt * 256 + nunit * 4;
  int wbo[4];                           // byte offsets of the 4 write slots
#pragma unroll
  for (int i = 0; i < 4; i++) {
    int n = nunit * 4 + i;
    int S = (n ^ (n >> 3)) & 7;
    wbo[i] = n * 128 + ((kunit ^ S) << 4);
  }

  f32x4 acc[8][4];
#pragma unroll
  for (int i = 0; i < 8; i++)
#pragma unroll
    for (int j = 0; j < 4; j++) {
      f32x4 z = {0.f, 0.f, 0.f, 0.f};
      acc[i][j] = z;
    }
  bf16x8 a[4][2], b[4][2];

  // ---- fragment read offsets
  int aof0 = (wm * 128 + l15) * 128 + ((lhi ^ (l15 & 7)) << 4);
  int aof1 = (wm * 128 + l15) * 128 + (((4 + lhi) ^ (l15 & 7)) << 4);
  int boff[4][2];
#pragma unroll
  for (int nf = 0; nf < 4; nf++) {
    int r = wn * 64 + nf * 16 + l15;
    int Sr = (r ^ (r >> 3)) & 7;
    boff[nf][0] = r * 128 + ((lhi ^ Sr) << 4);
    boff[nf][1] = r * 128 + (((4 + lhi) ^ Sr) << 4);
  }

#define LGKM0()                                                              \
  do {                                                                       \
    asm volatile("s_waitcnt lgkmcnt(0)" ::: "memory");                       \
    __builtin_amdgcn_sched_barrier(0);                                       \
  } while (0)

#define MFMA_QUAD(mh, nh)                                                    \
  do {                                                                       \
    __builtin_amdgcn_s_setprio(1);                                           \
    _Pragma("unroll") for (int mf = 0; mf < 4; mf++)                         \
        _Pragma("unroll") for (int nf = 0; nf < 2; nf++)                     \
            _Pragma("unroll") for (int kk = 0; kk < 2; kk++)                 \
                acc[(mh)*4 + mf][(nh)*2 + nf] = __builtin_amdgcn_mfma_f32_16x16x32_bf16( \
                    a[mf][kk], b[(nh)*2 + nf][kk], acc[(mh)*4 + mf][(nh)*2 + nf], 0, 0, 0); \
    __builtin_amdgcn_s_setprio(0);                                           \
  } while (0)

  // ---- prologue: A(0) via DMA; L(0) -> B slot 0
  STAGE_HALF_A(0, 0); STAGE_HALF_A(0, 1);
  {
    float4 P[8];
#pragma unroll
    for (int j = 0; j < 8; j++)
      P[j] = *reinterpret_cast<const float4*>(gWb + (size_t)j * NN);
    asm volatile("s_waitcnt vmcnt(0)" ::: "memory");  // L(0) regs + A(0) resident
    __builtin_amdgcn_sched_barrier(0);
    char* wB = smc + 65536;  // slot 0
#pragma unroll
    for (int i = 0; i < 4; i++) {
      uint4 v;
      v.x = pkbf(P[0][i], P[1][i]); v.y = pkbf(P[2][i], P[3][i]);
      v.z = pkbf(P[4][i], P[5][i]); v.w = pkbf(P[6][i], P[7][i]);
      *reinterpret_cast<uint4*>(wB + wbo[i]) = v;
    }
  }
  LGKM0();
  __builtin_amdgcn_s_barrier();

  for (int t = 0; t < KT; t++) {
    const char* pA = smc + (t & 1) * 32768;
    const char* pB = smc + 65536 + (t & 1) * 32768;
    char* wB = smc + 65536 + ((t + 1) & 1) * 32768;
    float4 L0, L1, L2, L3, L4, L5, L6, L7;

    // issue next-tile loads first: 8 L (oldest), then 4 A-DMA
    if (t + 1 < KT) {
      const float* g = gWb + (size_t)(t + 1) * 64 * NN;
      L0 = *reinterpret_cast<const float4*>(g);
      L1 = *reinterpret_cast<const float4*>(g + (size_t)1 * NN);
      L2 = *reinterpret_cast<const float4*>(g + (size_t)2 * NN);
      L3 = *reinterpret_cast<const float4*>(g + (size_t)3 * NN);
      L4 = *reinterpret_cast<const float4*>(g + (size_t)4 * NN);
      L5 = *reinterpret_cast<const float4*>(g + (size_t)5 * NN);
      L6 = *reinterpret_cast<const float4*>(g + (size_t)6 * NN);
      L7 = *reinterpret_cast<const float4*>(g + (size_t)7 * NN);
      STAGE_HALF_A(t + 1, 0); STAGE_HALF_A(t + 1, 1);
    }

    // ---- half 1: a03 + all b frags; 32 MFMA
#pragma unroll
    for (int mf = 0; mf < 4; mf++) {
      a[mf][0] = *reinterpret_cast<const bf16x8*>(pA + aof0 + mf * 2048);
      a[mf][1] = *reinterpret_cast<const bf16x8*>(pA + aof1 + mf * 2048);
    }
#pragma unroll
    for (int nf = 0; nf < 4; nf++) {
      b[nf][0] = *reinterpret_cast<const bf16x8*>(pB + boff[nf][0]);
      b[nf][1] = *reinterpret_cast<const bf16x8*>(pB + boff[nf][1]);
    }
    LGKM0();
    MFMA_QUAD(0, 0);
    MFMA_QUAD(0, 1);

    // ---- half 2: a47 (reuse a[] regs); 32 MFMA
#pragma unroll
    for (int mf = 0; mf < 4; mf++) {
      a[mf][0] = *reinterpret_cast<const bf16x8*>(pA + aof0 + (4 + mf) * 2048);
      a[mf][1] = *reinterpret_cast<const bf16x8*>(pA + aof1 + (4 + mf) * 2048);
    }
    LGKM0();
    MFMA_QUAD(1, 0);
    MFMA_QUAD(1, 1);

    // ---- stage B(t+1) from L regs; single barrier
    if (t + 1 < KT) {
      asm volatile("s_waitcnt vmcnt(4)" ::: "memory");  // L retired; ADMA in flight
      __builtin_amdgcn_sched_barrier(0);
#pragma unroll
      for (int i = 0; i < 4; i++) {
        uint4 v;
        v.x = pkbf(L0[i], L1[i]); v.y = pkbf(L2[i], L3[i]);
        v.z = pkbf(L4[i], L5[i]); v.w = pkbf(L6[i], L7[i]);
        *reinterpret_cast<uint4*>(wB + wbo[i]) = v;
      }
      asm volatile("s_waitcnt vmcnt(0) lgkmcnt(0)" ::: "memory");  // ADMA + B-writes drained
      __builtin_amdgcn_sched_barrier(0);
      __builtin_amdgcn_s_barrier();
    }
  }
#undef STAGE_HALF_A
#undef MFMA_QUAD
#undef LGKM0

  // epilogue: D row = lhi*4+reg, col = l15 (verified C/D layout); bf16 out
#pragma unroll
  for (int mf = 0; mf < 8; mf++) {
#pragma unroll
    for (int nf = 0; nf < 4; nf++) {
#pragma unroll
      for (int rg = 0; rg < 4; rg++) {
        float v = acc[mf][nf][rg];
        int grow = mt * 256 + wm * 128 + mf * 16 + lhi * 4 + rg;
        int gcol = nt * 256 + wn * 64 + nf * 16 + l15;
        size_t off = ((size_t)e * CAP + grow) * NN + gcol;
        if constexpr (SILU) v = v / (1.0f + __expf(-v));  // silu
        Cout[off] = f2bf(v);
      }
    }
  }
}

// ------------------------------------------- weighted combine (no atomics)
// wave per token: lane reads uint4 (8 bf16) per slot row, writes 2 float4.
__global__ void k_combine(const u16* __restrict__ yws, const int* __restrict__ slot_pos,
                          const float* __restrict__ w, float* __restrict__ out) {
  int tk = blockIdx.x * 4 + (threadIdx.x >> 6);
  int lane = threadIdx.x & 63;
  int p0 = slot_pos[2 * tk], p1 = slot_pos[2 * tk + 1];
  float w0 = w[2 * tk], w1 = w[2 * tk + 1];
  uint4 ua = reinterpret_cast<const uint4*>(yws + (size_t)p0 * HID)[lane];
  uint4 ub = reinterpret_cast<const uint4*>(yws + (size_t)p1 * HID)[lane];
  float4 o0, o1;
  o0.x = w0 * bf2f(ua.x & 0xffffu) + w1 * bf2f(ub.x & 0xffffu);
  o0.y = w0 * bf2f(ua.x >> 16) + w1 * bf2f(ub.x >> 16);
  o0.z = w0 * bf2f(ua.y & 0xffffu) + w1 * bf2f(ub.y & 0xffffu);
  o0.w = w0 * bf2f(ua.y >> 16) + w1 * bf2f(ub.y >> 16);
  o1.x = w0 * bf2f(ua.z & 0xffffu) + w1 * bf2f(ub.z & 0xffffu);
  o1.y = w0 * bf2f(ua.z >> 16) + w1 * bf2f(ub.z >> 16);
  o1.z = w0 * bf2f(ua.w & 0xffffu) + w1 * bf2f(ub.w & 0xffffu);
  o1.w = w0 * bf2f(ua.w >> 16) + w1 * bf2f(ub.w >> 16);
  float4* dst = reinterpret_cast<float4*>(out + (size_t)tk * HID + lane * 8);
  dst[0] = o0;
  dst[1] = o1;
}

// ---------------------------------------------------------------- launcher
extern "C" void kernel_launch(void* const* d_in, const int* in_sizes, int n_in,
                              void* d_out, int out_size, void* d_ws, size_t ws_size,
                              hipStream_t stream) {
  const float* hs = (const float*)d_in[0];
  const float* wts = (const float*)d_in[1];
  const int* ids = (const int*)d_in[2];
  const float* W1 = (const float*)d_in[3];
  const float* W2 = (const float*)d_in[4];
  float* out = (float*)d_out;

  char* ws = (char*)d_ws;
  size_t o = 0;
  int* cnt = (int*)(ws + o);       o += 1024;
  int* slot_pos = (int*)(ws + o);  o += (size_t)NASSIGN * 4;
  int* tok_of = (int*)(ws + o);    o += (size_t)NASSIGN * 4;
  o = (o + 255) & ~(size_t)255;
  u16* Xg = (u16*)(ws + o);        o += (size_t)NASSIGN * HID * 2;      // 32 MB
  u16* hid = (u16*)(ws + o);       o += (size_t)NASSIGN * FFN * 2;      // 64 MB
  u16* yws = (u16*)(ws + o);       o += (size_t)NASSIGN * HID * 2;      // 32 MB

  hipMemsetAsync(cnt, 0, NEXP * sizeof(int), stream);
  k_route<<<(NASSIGN + 255) / 256, 256, 0, stream>>>(ids, cnt, tok_of, slot_pos);
  k_gather<<<NASSIGN / 4, 256, 0, stream>>>(hs, tok_of, Xg);
  k_gemm<HID, FFN, true><<<NEXP * (CAP / 256) * (FFN / 256), 512, 0, stream>>>(Xg, W1, hid);
  k_gemm<FFN, HID, false><<<NEXP * (CAP / 256) * (HID / 256), 512, 0, stream>>>(hid, W2, yws);
  k_combine<<<B_TOK / 4, 256, 0, stream>>>(yws, slot_pos, wts, out);
}